// Round 6
// baseline (372.216 us; speedup 1.0000x reference)
//
#include <hip/hip_runtime.h>
#include <math.h>

constexpr int B = 2, A = 900, ED = 256, NG = 8, NCAM = 6, NL = 4, NP = 7;
constexpr int NJ = NG * NCAM * NL * NP;   // 1344
constexpr int NBA = B * A;                // 1800
constexpr int NE = NCAM * NL * NP;        // 168 point-level entries

// transpose-kernel partition: 336 w_fc tiles + 231 feat tiles per (b,cam)
constexpr int NWFB = 336;                 // 42 x 8 tiles of 32x32 (w_fc)
constexpr int TPB  = 231;                 // 176(l1) + 44(l2) + 11(l3)
constexpr int NTRB = TPB * B * NCAM;      // 2772

__constant__ float FIXS[NP][3] = {
  {0.f,0.f,0.f},{0.45f,0.f,0.f},{-0.45f,0.f,0.f},
  {0.f,0.45f,0.f},{0.f,-0.45f,0.f},{0.f,0.f,0.45f},{0.f,0.f,-0.45f}};

__constant__ int cH[NL]  = {64,32,16,8};
__constant__ int cW[NL]  = {176,88,44,22};
__constant__ int cHW[NL] = {11264,2816,704,176};
// float offsets of levels 1..3 inside tfeat (level 0 stays native channel-first)
__constant__ long long cLOFF[NL] = {0LL, 0LL, 8650752LL, 10813440LL};

// ---- merged coalesced transposes: w_fc -> wt, lvls 1-3 -> channel-last ----
// read: lanes span contiguous px (4 x 256B segments per wave-instr);
// write: lanes span contiguous ch. Scalar LDS, padded (conflict-free).
__global__ __launch_bounds__(256) void k_prep_tr(
    const float* __restrict__ f1, const float* __restrict__ f2,
    const float* __restrict__ f3, const float* __restrict__ w_fc,
    float* __restrict__ tfeat, float* __restrict__ wt)
{
  __shared__ float smem[64 * 65];   // 16.6 KB (lvl3 path uses 16*257=4112)
  const int bid = blockIdx.x;
  const int t   = threadIdx.x;

  if (bid < NWFB) {
    // ---- w_fc [1344,256] -> wt [256,1344], 32x32 tiles (42 x 8) ----
    const int r0 = (bid >> 3) * 32, c0 = (bid & 7) * 32;
    const int tx = t & 31, ty = t >> 5;   // (32,8)
#pragma unroll
    for (int i = 0; i < 4; ++i)
      smem[(ty + 8*i)*33 + tx] = w_fc[(size_t)(r0 + ty + 8*i)*ED + c0 + tx];
    __syncthreads();
#pragma unroll
    for (int i = 0; i < 4; ++i)
      wt[(size_t)(c0 + ty + 8*i)*NJ + r0 + tx] = smem[tx*33 + ty + 8*i];
    return;
  }

  // ---- feature channel-last transpose ----
  const int fb = bid - NWFB;
  const int bc = fb / TPB;
  const int bx = fb % TPB;
  int lvl, px0, ch0;
  const float* src;
  if (bx < 176)      { lvl = 1; src = f1; px0 = (bx >> 2) * 64;         ch0 = (bx & 3) * 64; }
  else if (bx < 220) { lvl = 2; src = f2; px0 = ((bx - 176) >> 2) * 64; ch0 = ((bx - 176) & 3) * 64; }
  else               { lvl = 3; src = f3; px0 = (bx - 220) * 16;        ch0 = 0; }
  const int HW = cHW[lvl];
  const float* in = src + (size_t)bc * ED * HW;
  float* outp = tfeat + cLOFF[lvl] + (size_t)bc * HW * ED;

  if (lvl < 3) {
    // 64 px x 64 ch tile
    const int pxl = t & 15, cr = t >> 4;          // px quad, ch row
#pragma unroll
    for (int i = 0; i < 4; ++i) {
      const int ch = cr + 16*i;
      const float4 v = *(const float4*)(in + (size_t)(ch0 + ch)*HW + px0 + 4*pxl);
      smem[(4*pxl+0)*65 + ch] = v.x;
      smem[(4*pxl+1)*65 + ch] = v.y;
      smem[(4*pxl+2)*65 + ch] = v.z;
      smem[(4*pxl+3)*65 + ch] = v.w;
    }
    __syncthreads();
    const int chl = t & 15, pw = t >> 4;
#pragma unroll
    for (int i = 0; i < 4; ++i) {
      const int px = pw + 16*i;
      float4 v;
      v.x = smem[px*65 + 4*chl + 0];
      v.y = smem[px*65 + 4*chl + 1];
      v.z = smem[px*65 + 4*chl + 2];
      v.w = smem[px*65 + 4*chl + 3];
      *(float4*)(outp + (size_t)(px0 + px)*ED + ch0 + 4*chl) = v;
    }
  } else {
    // 16 px x 256 ch tile (HW=176 = 11 x 16)
    const int pxl = t & 3, cr = t >> 2;           // cr 0..63
#pragma unroll
    for (int i = 0; i < 4; ++i) {
      const int ch = cr + 64*i;
      const float4 v = *(const float4*)(in + (size_t)ch*HW + px0 + 4*pxl);
      smem[(4*pxl+0)*257 + ch] = v.x;
      smem[(4*pxl+1)*257 + ch] = v.y;
      smem[(4*pxl+2)*257 + ch] = v.z;
      smem[(4*pxl+3)*257 + ch] = v.w;
    }
    __syncthreads();
    const int chl = t & 63, pw = t >> 6;
#pragma unroll
    for (int i = 0; i < 4; ++i) {
      const int px = pw + 4*i;
      float4 v;
      v.x = smem[px*257 + 4*chl + 0];
      v.y = smem[px*257 + 4*chl + 1];
      v.z = smem[px*257 + 4*chl + 2];
      v.w = smem[px*257 + 4*chl + 3];
      *(float4*)(outp + (size_t)(px0 + px)*ED + 4*chl) = v;
    }
  }
}

// ------- FC: wraw[1800,1344] = (inst+emb) @ wt + b_fc, wt = w_fc^T [256,1344] -------
__global__ __launch_bounds__(192) void k_fc(const float* __restrict__ inst,
    const float* __restrict__ emb, const float* __restrict__ wt,
    const float* __restrict__ b_fc, float* __restrict__ wraw)
{
  __shared__ float fsh[8][ED];
  const int a0 = blockIdx.x * 8;
  const int j  = blockIdx.y * 192 + threadIdx.x;
  const int t  = threadIdx.x;

  for (int i = t; i < 8 * ED; i += 192) {
    const int a = i >> 8, k = i & 255;
    const size_t idx = (size_t)(a0 + a) * ED + k;
    fsh[a][k] = inst[idx] + emb[idx];
  }
  __syncthreads();

  float acc[8] = {0.f,0.f,0.f,0.f,0.f,0.f,0.f,0.f};
  for (int k = 0; k < ED; k += 4) {
    float w0 = wt[(size_t)(k+0)*NJ + j];
    float w1 = wt[(size_t)(k+1)*NJ + j];
    float w2 = wt[(size_t)(k+2)*NJ + j];
    float w3 = wt[(size_t)(k+3)*NJ + j];
#pragma unroll
    for (int a = 0; a < 8; ++a)
      acc[a] += w0*fsh[a][k] + w1*fsh[a][k+1] + w2*fsh[a][k+2] + w3*fsh[a][k+3];
  }
  const float bj = b_fc[j];
#pragma unroll
  for (int a = 0; a < 8; ++a)
    wraw[(size_t)(a0+a)*NJ + j] = acc[a] + bj;
}

// -- fused: softmax + projection + compacted gather + output projection --
// one block per anchor: softmax over ALL NE entries once, gather into
// fused_sh[256], then out = fused_sh @ w_out^T + b_out written directly.
template<bool CL>
__global__ __launch_bounds__(256) void k_sample_o(
    const float* __restrict__ anchor, const float* __restrict__ proj,
    const float* __restrict__ wh, const float* __restrict__ wraw,
    const float* __restrict__ tfeat,
    const float* __restrict__ f0, const float* __restrict__ f1,
    const float* __restrict__ f2, const float* __restrict__ f3,
    const float* __restrict__ w_out, const float* __restrict__ b_out,
    float* __restrict__ out)
{
  __shared__ float wsh[NJ];              // [g][e] layout (conflict-free)
  __shared__ float gridsh[NCAM][NP][2];
  __shared__ const float* cptr[NE][4];   // 4 pre-clamped tap pointers (ch 0)
  __shared__ float4 cwt[NE];             // validity-masked bilinear weights
  __shared__ int2   cmeta[NE];           // x=chstep, y=entry idx
  __shared__ int wcnt[4];
  __shared__ float fused_sh[ED];

  const int ba = blockIdx.x;
  const int b  = ba / A;
  const int t  = threadIdx.x;

  for (int j = t; j < NJ; j += 256)
    wsh[(j & 7) * NE + (j >> 3)] = wraw[(size_t)ba*NJ + j];

  if (t < NCAM*NP) {
    const int c = t / NP, p = t % NP;
    const float* an = anchor + (size_t)ba * 8;
    const float sx = expf(an[3]), sy = expf(an[4]), sz = expf(an[5]);
    const float sn = an[6], cs = an[7];
    const float kx = FIXS[p][0]*sx, ky = FIXS[p][1]*sy, kz = FIXS[p][2]*sz;
    const float px = cs*kx - sn*ky + an[0];
    const float py = sn*kx + cs*ky + an[1];
    const float pz = kz + an[2];
    const float* P = proj + ((size_t)(b*NCAM + c))*16;
    const float X = P[0]*px + P[1]*py + P[2]*pz  + P[3];
    const float Y = P[4]*px + P[5]*py + P[6]*pz  + P[7];
    const float Z = P[8]*px + P[9]*py + P[10]*pz + P[11];
    const float zc  = fmaxf(Z, 1e-5f);
    const float whx = fmaxf(wh[(b*NCAM+c)*2+0], 1e-5f);
    const float why = fmaxf(wh[(b*NCAM+c)*2+1], 1e-5f);
    gridsh[c][p][0] = (X/zc/whx)*2.f - 1.f;
    gridsh[c][p][1] = (Y/zc/why)*2.f - 1.f;
  }
  __syncthreads();

  // entry e = t for t < NE
  bool valid = false;
  int chstep = 0;
  float4 w4 = make_float4(0.f,0.f,0.f,0.f);
  const float *p00=nullptr, *p10=nullptr, *p01=nullptr, *p11=nullptr;
  if (t < NE) {
    const int e = t;
    const int c = e / (NL*NP); const int r = e % (NL*NP);
    const int l = r / NP, p = r % NP;
    const int Wl = cW[l], Hl = cH[l], HWl = cHW[l];
    const float gx = (gridsh[c][p][0] + 1.f) * (Wl * 0.5f) - 0.5f;
    const float gy = (gridsh[c][p][1] + 1.f) * (Hl * 0.5f) - 0.5f;
    const float x0f = floorf(gx), y0f = floorf(gy);
    const bool vx0 = (x0f >=  0.f) & (x0f <= (float)(Wl-1));
    const bool vx1 = (x0f >= -1.f) & (x0f <= (float)(Wl-2));
    const bool vy0 = (y0f >=  0.f) & (y0f <= (float)(Hl-1));
    const bool vy1 = (y0f >= -1.f) & (y0f <= (float)(Hl-2));
    if (vx0|vx1|vy0|vy1) {
      const float wx1 = gx - x0f, wy1 = gy - y0f;
      // clamp both tap coords into the image; invalid taps get weight 0
      const int x0 = (int)fmaxf(fminf(x0f,        (float)(Wl-1)), 0.f);
      const int x1 = (int)fmaxf(fminf(x0f + 1.f,  (float)(Wl-1)), 0.f);
      const int y0 = (int)fmaxf(fminf(y0f,        (float)(Hl-1)), 0.f);
      const int y1 = (int)fmaxf(fminf(y0f + 1.f,  (float)(Hl-1)), 0.f);
      w4 = make_float4((1.f-wx1)*(1.f-wy1)*(vx0&&vy0),
                       wx1*(1.f-wy1)*(vx1&&vy0),
                       (1.f-wx1)*wy1*(vx0&&vy1),
                       wx1*wy1*(vx1&&vy1));
      if (w4.x != 0.f || w4.y != 0.f || w4.z != 0.f || w4.w != 0.f) {
        const float* base;
        int estep;  // element stride for one pixel step
        if (CL && l >= 1) {
          base = tfeat + cLOFF[l] + (size_t)(b*NCAM + c) * HWl * ED;
          estep = ED; chstep = 1;
        } else {
          const float* fp = (l==0)?f0:(l==1)?f1:(l==2)?f2:f3;
          base = fp + (size_t)(b*NCAM + c) * ED * HWl;
          estep = 1; chstep = HWl;
        }
        p00 = base + (size_t)(y0*Wl + x0) * estep;
        p10 = base + (size_t)(y0*Wl + x1) * estep;
        p01 = base + (size_t)(y1*Wl + x0) * estep;
        p11 = base + (size_t)(y1*Wl + x1) * estep;
        valid = true;
      }
    }
  }

  const unsigned long long mask = __ballot(valid);
  const int lane = t & 63, wv = t >> 6;
  if (lane == 0) wcnt[wv] = __popcll(mask);
  __syncthreads();
  int off = 0, nv = 0;
#pragma unroll
  for (int i = 0; i < 4; ++i) { if (i < wv) off += wcnt[i]; nv += wcnt[i]; }
  if (valid) {
    const int pos = off + __popcll(mask & ((1ull << lane) - 1ull));
    cptr[pos][0] = p00; cptr[pos][1] = p10; cptr[pos][2] = p01; cptr[pos][3] = p11;
    cwt[pos]   = w4;
    cmeta[pos] = make_int2(chstep, t);
  }

  // group softmax over ALL entries
  {
    const int g = t >> 5, ln = t & 31;
    float* wg = wsh + g * NE;
    float m = -3.4e38f;
    for (int i = ln; i < NE; i += 32) m = fmaxf(m, wg[i]);
#pragma unroll
    for (int mk = 16; mk >= 1; mk >>= 1) m = fmaxf(m, __shfl_xor(m, mk));
    float s = 0.f;
    for (int i = ln; i < NE; i += 32) {
      const float ev = expf(wg[i] - m);
      wg[i] = ev;
      s += ev;
    }
#pragma unroll
    for (int mk = 16; mk >= 1; mk >>= 1) s += __shfl_xor(s, mk);
    const float inv = 1.f / s;
    for (int i = ln; i < NE; i += 32) wg[i] *= inv;
  }
  __syncthreads();

  float acc = 0.f;
  const int g = t >> 5;
#pragma unroll 4
  for (int i = 0; i < nv; ++i) {
    const int2 m = cmeta[i];
    const size_t toff = (size_t)t * m.x;
    const float4 w = cwt[i];
    const float aw = wsh[g*NE + m.y];
    const float v00 = cptr[i][0][toff];
    const float v10 = cptr[i][1][toff];
    const float v01 = cptr[i][2][toff];
    const float v11 = cptr[i][3][toff];
    acc += aw * (w.x*v00 + w.y*v10 + w.z*v01 + w.w*v11);
  }
  fused_sh[t] = acc;
  __syncthreads();

  // out[ba][t] = dot(w_out row t, fused_sh) + b_out[t]
  float o = 0.f;
  for (int i = 0; i < ED; i += 4) {
    const float4 wv4 = *(const float4*)&w_out[(size_t)t*ED + i];
    const float4 fv  = *(const float4*)&fused_sh[i];
    o += wv4.x*fv.x + wv4.y*fv.y + wv4.z*fv.z + wv4.w*fv.w;
  }
  out[(size_t)ba*ED + t] = o + b_out[t];
}

extern "C" void kernel_launch(void* const* d_in, const int* in_sizes, int n_in,
                              void* d_out, int out_size, void* d_ws, size_t ws_size,
                              hipStream_t stream) {
  const float* inst   = (const float*)d_in[0];
  const float* anchor = (const float*)d_in[1];
  const float* emb    = (const float*)d_in[2];
  const float* f0 = (const float*)d_in[3];
  const float* f1 = (const float*)d_in[4];
  const float* f2 = (const float*)d_in[5];
  const float* f3 = (const float*)d_in[6];
  const float* proj  = (const float*)d_in[7];
  const float* wh    = (const float*)d_in[8];
  const float* w_fc  = (const float*)d_in[9];
  const float* b_fc  = (const float*)d_in[10];
  const float* w_out = (const float*)d_in[11];
  const float* b_out = (const float*)d_in[12];
  float* out = (float*)d_out;
  float* ws  = (float*)d_ws;

  const size_t TFEAT = 11354112ULL;   // levels 1-3 channel-last, floats
  const size_t WRAW  = (size_t)NBA * NJ;
  const size_t WT    = (size_t)ED * NJ;
  const bool tr = ws_size >= (TFEAT + WRAW + WT) * sizeof(float);

  float* tfeat = ws;
  float* wraw  = tr ? (ws + TFEAT) : ws;
  float* wt    = wraw + WRAW;

  // merged: w_fc transpose (336 blocks) + channel-last feat transpose (2772)
  k_prep_tr<<<NWFB + (tr ? NTRB : 0), 256, 0, stream>>>(f1, f2, f3, w_fc,
                                                        tfeat, wt);

  k_fc<<<dim3(NBA / 8, 7), 192, 0, stream>>>(inst, emb, wt, b_fc, wraw);

  if (tr)
    k_sample_o<true><<<NBA, 256, 0, stream>>>(anchor, proj, wh, wraw, tfeat,
        f0, f1, f2, f3, w_out, b_out, out);
  else
    k_sample_o<false><<<NBA, 256, 0, stream>>>(anchor, proj, wh, wraw, tfeat,
        f0, f1, f2, f3, w_out, b_out, out);
}

// Round 7
// 370.669 us; speedup vs baseline: 1.0042x; 1.0042x over previous
//
#include <hip/hip_runtime.h>
#include <math.h>

constexpr int B = 2, A = 900, ED = 256, NG = 8, NCAM = 6, NL = 4, NP = 7;
constexpr int NJ = NG * NCAM * NL * NP;   // 1344
constexpr int NBA = B * A;                // 1800
constexpr int NE = NCAM * NL * NP;        // 168 point-level entries
constexpr int SPLIT = 2;                  // entry-loop split across blocks
constexpr int EHALF = NE / SPLIT;         // 84

// transpose partition: 336 w_fc tiles + 935 feat tiles per (b,cam)
constexpr int NWFB = 336;                 // 42 x 8 tiles of 32x32 (w_fc)
constexpr int TPB  = 935;                 // 704(l0)+176(l1)+44(l2)+11(l3)
constexpr int NTRB = TPB * B * NCAM;      // 11220

__constant__ float FIXS[NP][3] = {
  {0.f,0.f,0.f},{0.45f,0.f,0.f},{-0.45f,0.f,0.f},
  {0.f,0.45f,0.f},{0.f,-0.45f,0.f},{0.f,0.f,0.45f},{0.f,0.f,-0.45f}};

__constant__ int cH[NL]  = {64,32,16,8};
__constant__ int cW[NL]  = {176,88,44,22};
__constant__ int cHW[NL] = {11264,2816,704,176};
// float offsets of levels 0..3 inside tfeat (ALL levels channel-last)
__constant__ long long cLOFF[NL] = {0LL, 34603008LL, 43253760LL, 45416448LL};

// ---- merged coalesced transposes: w_fc -> wt, lvls 0-3 -> channel-last ----
// read: lanes span contiguous px (4 x 256B segments per wave-instr);
// write: lanes span contiguous ch. Scalar LDS, padded (conflict-free).
__global__ __launch_bounds__(256) void k_prep_tr(
    const float* __restrict__ f0, const float* __restrict__ f1,
    const float* __restrict__ f2, const float* __restrict__ f3,
    const float* __restrict__ w_fc,
    float* __restrict__ tfeat, float* __restrict__ wt)
{
  __shared__ float smem[64 * 65];   // 16.6 KB (lvl3 path uses 16*257=4112)
  const int bid = blockIdx.x;
  const int t   = threadIdx.x;

  if (bid < NWFB) {
    // ---- w_fc [1344,256] -> wt [256,1344], 32x32 tiles (42 x 8) ----
    const int r0 = (bid >> 3) * 32, c0 = (bid & 7) * 32;
    const int tx = t & 31, ty = t >> 5;   // (32,8)
#pragma unroll
    for (int i = 0; i < 4; ++i)
      smem[(ty + 8*i)*33 + tx] = w_fc[(size_t)(r0 + ty + 8*i)*ED + c0 + tx];
    __syncthreads();
#pragma unroll
    for (int i = 0; i < 4; ++i)
      wt[(size_t)(c0 + ty + 8*i)*NJ + r0 + tx] = smem[tx*33 + ty + 8*i];
    return;
  }

  // ---- feature channel-last transpose, all levels ----
  const int fb = bid - NWFB;
  const int bc = fb / TPB;
  const int bx = fb % TPB;
  int lvl, px0, ch0;
  const float* src;
  if (bx < 704)      { lvl = 0; src = f0; px0 = (bx >> 2) * 64;         ch0 = (bx & 3) * 64; }
  else if (bx < 880) { lvl = 1; src = f1; px0 = ((bx - 704) >> 2) * 64; ch0 = ((bx - 704) & 3) * 64; }
  else if (bx < 924) { lvl = 2; src = f2; px0 = ((bx - 880) >> 2) * 64; ch0 = ((bx - 880) & 3) * 64; }
  else               { lvl = 3; src = f3; px0 = (bx - 924) * 16;        ch0 = 0; }
  const int HW = cHW[lvl];
  const float* in = src + (size_t)bc * ED * HW;
  float* outp = tfeat + cLOFF[lvl] + (size_t)bc * HW * ED;

  if (lvl < 3) {
    // 64 px x 64 ch tile (HW: 11264=176*64, 2816=44*64, 704=11*64)
    const int pxl = t & 15, cr = t >> 4;          // px quad, ch row
#pragma unroll
    for (int i = 0; i < 4; ++i) {
      const int ch = cr + 16*i;
      const float4 v = *(const float4*)(in + (size_t)(ch0 + ch)*HW + px0 + 4*pxl);
      smem[(4*pxl+0)*65 + ch] = v.x;
      smem[(4*pxl+1)*65 + ch] = v.y;
      smem[(4*pxl+2)*65 + ch] = v.z;
      smem[(4*pxl+3)*65 + ch] = v.w;
    }
    __syncthreads();
    const int chl = t & 15, pw = t >> 4;
#pragma unroll
    for (int i = 0; i < 4; ++i) {
      const int px = pw + 16*i;
      float4 v;
      v.x = smem[px*65 + 4*chl + 0];
      v.y = smem[px*65 + 4*chl + 1];
      v.z = smem[px*65 + 4*chl + 2];
      v.w = smem[px*65 + 4*chl + 3];
      *(float4*)(outp + (size_t)(px0 + px)*ED + ch0 + 4*chl) = v;
    }
  } else {
    // 16 px x 256 ch tile (HW=176 = 11 x 16)
    const int pxl = t & 3, cr = t >> 2;           // cr 0..63
#pragma unroll
    for (int i = 0; i < 4; ++i) {
      const int ch = cr + 64*i;
      const float4 v = *(const float4*)(in + (size_t)ch*HW + px0 + 4*pxl);
      smem[(4*pxl+0)*257 + ch] = v.x;
      smem[(4*pxl+1)*257 + ch] = v.y;
      smem[(4*pxl+2)*257 + ch] = v.z;
      smem[(4*pxl+3)*257 + ch] = v.w;
    }
    __syncthreads();
    const int chl = t & 63, pw = t >> 6;
#pragma unroll
    for (int i = 0; i < 4; ++i) {
      const int px = pw + 4*i;
      float4 v;
      v.x = smem[px*257 + 4*chl + 0];
      v.y = smem[px*257 + 4*chl + 1];
      v.z = smem[px*257 + 4*chl + 2];
      v.w = smem[px*257 + 4*chl + 3];
      *(float4*)(outp + (size_t)(px0 + px)*ED + 4*chl) = v;
    }
  }
}

// ------- FC: wraw[1800,1344] = (inst+emb) @ wt + b_fc, wt = w_fc^T [256,1344] -------
__global__ __launch_bounds__(192) void k_fc(const float* __restrict__ inst,
    const float* __restrict__ emb, const float* __restrict__ wt,
    const float* __restrict__ b_fc, float* __restrict__ wraw)
{
  __shared__ float fsh[8][ED];
  const int a0 = blockIdx.x * 8;
  const int j  = blockIdx.y * 192 + threadIdx.x;
  const int t  = threadIdx.x;

  for (int i = t; i < 8 * ED; i += 192) {
    const int a = i >> 8, k = i & 255;
    const size_t idx = (size_t)(a0 + a) * ED + k;
    fsh[a][k] = inst[idx] + emb[idx];
  }
  __syncthreads();

  float acc[8] = {0.f,0.f,0.f,0.f,0.f,0.f,0.f,0.f};
  for (int k = 0; k < ED; k += 4) {
    float w0 = wt[(size_t)(k+0)*NJ + j];
    float w1 = wt[(size_t)(k+1)*NJ + j];
    float w2 = wt[(size_t)(k+2)*NJ + j];
    float w3 = wt[(size_t)(k+3)*NJ + j];
#pragma unroll
    for (int a = 0; a < 8; ++a)
      acc[a] += w0*fsh[a][k] + w1*fsh[a][k+1] + w2*fsh[a][k+2] + w3*fsh[a][k+3];
  }
  const float bj = b_fc[j];
#pragma unroll
  for (int a = 0; a < 8; ++a)
    wraw[(size_t)(a0+a)*NJ + j] = acc[a] + bj;
}

// ------- fused: softmax + projection + branchless compacted gather ----
// grid (NBA, SPLIT); CL=true: ALL levels channel-last from tfeat (coalesced
// 1KB taps). CL=false fallback: direct channel-first reads.
template<bool CL>
__global__ __launch_bounds__(256) void k_sample_h(
    const float* __restrict__ anchor, const float* __restrict__ proj,
    const float* __restrict__ wh, const float* __restrict__ wraw,
    const float* __restrict__ tfeat,
    const float* __restrict__ f0, const float* __restrict__ f1,
    const float* __restrict__ f2, const float* __restrict__ f3,
    float* __restrict__ fused)
{
  __shared__ float wsh[NJ];              // [g][e] layout (conflict-free)
  __shared__ float gridsh[NCAM][NP][2];
  __shared__ const float* cptr[EHALF][4]; // 4 pre-clamped tap pointers (ch 0)
  __shared__ float4 cwt[EHALF];           // validity-masked bilinear weights
  __shared__ int2   cmeta[EHALF];         // x=chstep, y=entry idx
  __shared__ int wcnt[4];

  const int ba   = blockIdx.x;
  const int half = blockIdx.y;
  const int b    = ba / A;
  const int t    = threadIdx.x;

  for (int j = t; j < NJ; j += 256)
    wsh[(j & 7) * NE + (j >> 3)] = wraw[(size_t)ba*NJ + j];

  if (t < NCAM*NP) {
    const int c = t / NP, p = t % NP;
    const float* an = anchor + (size_t)ba * 8;
    const float sx = expf(an[3]), sy = expf(an[4]), sz = expf(an[5]);
    const float sn = an[6], cs = an[7];
    const float kx = FIXS[p][0]*sx, ky = FIXS[p][1]*sy, kz = FIXS[p][2]*sz;
    const float px = cs*kx - sn*ky + an[0];
    const float py = sn*kx + cs*ky + an[1];
    const float pz = kz + an[2];
    const float* P = proj + ((size_t)(b*NCAM + c))*16;
    const float X = P[0]*px + P[1]*py + P[2]*pz  + P[3];
    const float Y = P[4]*px + P[5]*py + P[6]*pz  + P[7];
    const float Z = P[8]*px + P[9]*py + P[10]*pz + P[11];
    const float zc  = fmaxf(Z, 1e-5f);
    const float whx = fmaxf(wh[(b*NCAM+c)*2+0], 1e-5f);
    const float why = fmaxf(wh[(b*NCAM+c)*2+1], 1e-5f);
    gridsh[c][p][0] = (X/zc/whx)*2.f - 1.f;
    gridsh[c][p][1] = (Y/zc/why)*2.f - 1.f;
  }
  __syncthreads();

  // entries for this block: e = half*EHALF + (t if t < EHALF)
  bool valid = false;
  int chstep = 0;
  float4 w4 = make_float4(0.f,0.f,0.f,0.f);
  const float *p00=nullptr, *p10=nullptr, *p01=nullptr, *p11=nullptr;
  const int e = half * EHALF + t;
  if (t < EHALF) {
    const int c = e / (NL*NP); const int r = e % (NL*NP);
    const int l = r / NP, p = r % NP;
    const int Wl = cW[l], Hl = cH[l], HWl = cHW[l];
    const float gx = (gridsh[c][p][0] + 1.f) * (Wl * 0.5f) - 0.5f;
    const float gy = (gridsh[c][p][1] + 1.f) * (Hl * 0.5f) - 0.5f;
    const float x0f = floorf(gx), y0f = floorf(gy);
    const bool vx0 = (x0f >=  0.f) & (x0f <= (float)(Wl-1));
    const bool vx1 = (x0f >= -1.f) & (x0f <= (float)(Wl-2));
    const bool vy0 = (y0f >=  0.f) & (y0f <= (float)(Hl-1));
    const bool vy1 = (y0f >= -1.f) & (y0f <= (float)(Hl-2));
    if (vx0|vx1|vy0|vy1) {
      const float wx1 = gx - x0f, wy1 = gy - y0f;
      // clamp both tap coords into the image; invalid taps get weight 0
      const int x0 = (int)fmaxf(fminf(x0f,        (float)(Wl-1)), 0.f);
      const int x1 = (int)fmaxf(fminf(x0f + 1.f,  (float)(Wl-1)), 0.f);
      const int y0 = (int)fmaxf(fminf(y0f,        (float)(Hl-1)), 0.f);
      const int y1 = (int)fmaxf(fminf(y0f + 1.f,  (float)(Hl-1)), 0.f);
      w4 = make_float4((1.f-wx1)*(1.f-wy1)*(vx0&&vy0),
                       wx1*(1.f-wy1)*(vx1&&vy0),
                       (1.f-wx1)*wy1*(vx0&&vy1),
                       wx1*wy1*(vx1&&vy1));
      if (w4.x != 0.f || w4.y != 0.f || w4.z != 0.f || w4.w != 0.f) {
        const float* base;
        int estep;  // element stride for one pixel step
        if (CL) {
          base = tfeat + cLOFF[l] + (size_t)(b*NCAM + c) * HWl * ED;
          estep = ED; chstep = 1;
        } else {
          const float* fp = (l==0)?f0:(l==1)?f1:(l==2)?f2:f3;
          base = fp + (size_t)(b*NCAM + c) * ED * HWl;
          estep = 1; chstep = HWl;
        }
        p00 = base + (size_t)(y0*Wl + x0) * estep;
        p10 = base + (size_t)(y0*Wl + x1) * estep;
        p01 = base + (size_t)(y1*Wl + x0) * estep;
        p11 = base + (size_t)(y1*Wl + x1) * estep;
        valid = true;
      }
    }
  }

  const unsigned long long mask = __ballot(valid);
  const int lane = t & 63, wv = t >> 6;
  if (lane == 0) wcnt[wv] = __popcll(mask);
  __syncthreads();
  int off = 0, nv = 0;
#pragma unroll
  for (int i = 0; i < 4; ++i) { if (i < wv) off += wcnt[i]; nv += wcnt[i]; }
  if (valid) {
    const int pos = off + __popcll(mask & ((1ull << lane) - 1ull));
    cptr[pos][0] = p00; cptr[pos][1] = p10; cptr[pos][2] = p01; cptr[pos][3] = p11;
    cwt[pos]   = w4;
    cmeta[pos] = make_int2(chstep, e);
  }

  // group softmax over ALL entries (needed for correct normalization)
  {
    const int g = t >> 5, ln = t & 31;
    float* wg = wsh + g * NE;
    float m = -3.4e38f;
    for (int i = ln; i < NE; i += 32) m = fmaxf(m, wg[i]);
#pragma unroll
    for (int mk = 16; mk >= 1; mk >>= 1) m = fmaxf(m, __shfl_xor(m, mk));
    float s = 0.f;
    for (int i = ln; i < NE; i += 32) {
      const float ev = expf(wg[i] - m);
      wg[i] = ev;
      s += ev;
    }
#pragma unroll
    for (int mk = 16; mk >= 1; mk >>= 1) s += __shfl_xor(s, mk);
    const float inv = 1.f / s;
    for (int i = ln; i < NE; i += 32) wg[i] *= inv;
  }
  __syncthreads();

  float acc = 0.f;
  const int g = t >> 5;
#pragma unroll 4
  for (int i = 0; i < nv; ++i) {
    const int2 m = cmeta[i];
    const size_t toff = (size_t)t * m.x;
    const float4 w = cwt[i];
    const float aw = wsh[g*NE + m.y];
    const float v00 = cptr[i][0][toff];
    const float v10 = cptr[i][1][toff];
    const float v01 = cptr[i][2][toff];
    const float v11 = cptr[i][3][toff];
    acc += aw * (w.x*v00 + w.y*v10 + w.z*v01 + w.w*v11);
  }
  fused[((size_t)half * NBA + ba) * ED + t] = acc;
}

// ---------------- out = (fused0+fused1) @ w_out^T + b_out ----------------
__global__ __launch_bounds__(256) void k_out(const float* __restrict__ fused,
    const float* __restrict__ w_out, const float* __restrict__ b_out,
    float* __restrict__ out)
{
  __shared__ float fsh[8][ED];
  const int a0 = blockIdx.x * 8;
  const int t = threadIdx.x;
#pragma unroll
  for (int k = 0; k < 8; ++k)
    fsh[k][t] = fused[(size_t)(a0+k)*ED + t]
              + fused[(size_t)NBA*ED + (size_t)(a0+k)*ED + t];
  __syncthreads();
  float acc[8] = {0.f,0.f,0.f,0.f,0.f,0.f,0.f,0.f};
  for (int i = 0; i < ED; i += 4) {
    const float4 w4 = *(const float4*)&w_out[(size_t)t*ED + i];
#pragma unroll
    for (int k = 0; k < 8; ++k) {
      const float4 fv = *(const float4*)&fsh[k][i];
      acc[k] += w4.x*fv.x + w4.y*fv.y + w4.z*fv.z + w4.w*fv.w;
    }
  }
  const float bo = b_out[t];
#pragma unroll
  for (int k = 0; k < 8; ++k) out[(size_t)(a0+k)*ED + t] = acc[k] + bo;
}

extern "C" void kernel_launch(void* const* d_in, const int* in_sizes, int n_in,
                              void* d_out, int out_size, void* d_ws, size_t ws_size,
                              hipStream_t stream) {
  const float* inst   = (const float*)d_in[0];
  const float* anchor = (const float*)d_in[1];
  const float* emb    = (const float*)d_in[2];
  const float* f0 = (const float*)d_in[3];
  const float* f1 = (const float*)d_in[4];
  const float* f2 = (const float*)d_in[5];
  const float* f3 = (const float*)d_in[6];
  const float* proj  = (const float*)d_in[7];
  const float* wh    = (const float*)d_in[8];
  const float* w_fc  = (const float*)d_in[9];
  const float* b_fc  = (const float*)d_in[10];
  const float* w_out = (const float*)d_in[11];
  const float* b_out = (const float*)d_in[12];
  float* out = (float*)d_out;
  float* ws  = (float*)d_ws;

  const size_t TFEAT = 45957120ULL;   // ALL levels channel-last, floats
  const size_t WRAW  = (size_t)NBA * NJ;
  const size_t FUSED = (size_t)SPLIT * NBA * ED;
  const size_t WT    = (size_t)ED * NJ;
  const bool tr = ws_size >= (TFEAT + WRAW + FUSED + WT) * sizeof(float);

  float* tfeat  = ws;
  float* wraw   = tr ? (ws + TFEAT) : ws;
  float* fusedp = wraw + WRAW;
  float* wt     = fusedp + FUSED;

  // merged: w_fc transpose (336) + channel-last feat transpose (11220)
  k_prep_tr<<<NWFB + (tr ? NTRB : 0), 256, 0, stream>>>(f0, f1, f2, f3, w_fc,
                                                        tfeat, wt);

  k_fc<<<dim3(NBA / 8, 7), 192, 0, stream>>>(inst, emb, wt, b_fc, wraw);

  if (tr)
    k_sample_h<true><<<dim3(NBA, SPLIT), 256, 0, stream>>>(anchor, proj, wh,
        wraw, tfeat, f0, f1, f2, f3, fusedp);
  else
    k_sample_h<false><<<dim3(NBA, SPLIT), 256, 0, stream>>>(anchor, proj, wh,
        wraw, tfeat, f0, f1, f2, f3, fusedp);

  k_out<<<NBA / 8, 256, 0, stream>>>(fusedp, w_out, b_out, out);
}

// Round 9
// 342.815 us; speedup vs baseline: 1.0858x; 1.0813x over previous
//
#include <hip/hip_runtime.h>
#include <math.h>

constexpr int B = 2, A = 900, ED = 256, NG = 8, NCAM = 6, NL = 4, NP = 7;
constexpr int NJ = NG * NCAM * NL * NP;   // 1344
constexpr int NBA = B * A;                // 1800
constexpr int NE = NCAM * NL * NP;        // 168 point-level entries
constexpr int SPLIT = 2;                  // entry-loop split across blocks
constexpr int EHALF = NE / SPLIT;         // 84

// merged prep: 1575 FC blocks first, then 935 feat-transpose tiles per (b,cam)
constexpr int NFCB = 225 * 7;             // 1575 FC blocks (8 anchors x 192 j)
constexpr int TPB  = 935;                 // 704(l0)+176(l1)+44(l2)+11(l3)
constexpr int NTRB = TPB * B * NCAM;      // 11220

// native clang vector for nontemporal builtins (HIP float4 is rejected)
typedef float nfloat4 __attribute__((ext_vector_type(4)));

__constant__ float FIXS[NP][3] = {
  {0.f,0.f,0.f},{0.45f,0.f,0.f},{-0.45f,0.f,0.f},
  {0.f,0.45f,0.f},{0.f,-0.45f,0.f},{0.f,0.f,0.45f},{0.f,0.f,-0.45f}};

__constant__ int cH[NL]  = {64,32,16,8};
__constant__ int cW[NL]  = {176,88,44,22};
__constant__ int cHW[NL] = {11264,2816,704,176};
// float offsets of levels 0..3 inside tfeat (ALL levels channel-last)
__constant__ long long cLOFF[NL] = {0LL, 34603008LL, 43253760LL, 45416448LL};

// ---- merged: {FC role, blocks [0,NFCB)} + {channel-last transpose role} ----
// FC first so its VALU work overlaps the transpose's memory stalls.
// FC self-stages w_fc k-chunks via LDS (no wt buffer, no cross-block dep).
// Transpose: coalesced tiles; NT hints (read-once in, reuse-sparse out).
__global__ __launch_bounds__(256) void k_prep(
    const float* __restrict__ f0, const float* __restrict__ f1,
    const float* __restrict__ f2, const float* __restrict__ f3,
    const float* __restrict__ inst, const float* __restrict__ emb,
    const float* __restrict__ w_fc, const float* __restrict__ b_fc,
    float* __restrict__ tfeat, float* __restrict__ wraw)
{
  __shared__ float smem[4160];      // 16.6 KB both roles -> 8 blocks/CU
  const int bid = blockIdx.x;
  const int t   = threadIdx.x;

  if (bid < NFCB) {
    // ---------------- FC: wraw[a][j] = (inst+emb)[a] . w_fc[j] + b_fc ------
    float* fsh = smem;              // [8][256] features
    float* wts = smem + 2048;       // [8][193] staged w_fc^T chunk
    const int a0 = (bid / 7) * 8;
    const int j0 = (bid % 7) * 192;

    for (int i = t; i < 8 * ED; i += 256) {
      const int a = i >> 8, k = i & 255;
      const size_t idx = (size_t)(a0 + a) * ED + k;
      fsh[i] = inst[idx] + emb[idx];
    }

    float acc[8] = {0.f,0.f,0.f,0.f,0.f,0.f,0.f,0.f};
    for (int kc = 0; kc < 32; ++kc) {        // 32 chunks of 8 k
      __syncthreads();                        // fsh ready / wts reusable
      for (int idx = t; idx < 384; idx += 256) {
        const int row = idx >> 1, q = idx & 1;
        const float4 v = *(const float4*)&w_fc[(size_t)(j0 + row)*ED + kc*8 + 4*q];
        wts[(4*q+0)*193 + row] = v.x;
        wts[(4*q+1)*193 + row] = v.y;
        wts[(4*q+2)*193 + row] = v.z;
        wts[(4*q+3)*193 + row] = v.w;
      }
      __syncthreads();
      if (t < 192) {
        const int kb = kc * 8;
#pragma unroll
        for (int k = 0; k < 8; k += 4) {
          const float w0 = wts[(k+0)*193 + t];
          const float w1 = wts[(k+1)*193 + t];
          const float w2 = wts[(k+2)*193 + t];
          const float w3 = wts[(k+3)*193 + t];
#pragma unroll
          for (int a = 0; a < 8; ++a)
            acc[a] += w0*fsh[a*ED + kb+k]   + w1*fsh[a*ED + kb+k+1]
                    + w2*fsh[a*ED + kb+k+2] + w3*fsh[a*ED + kb+k+3];
        }
      }
    }
    if (t < 192) {
      const int j = j0 + t;
      const float bj = b_fc[j];
#pragma unroll
      for (int a = 0; a < 8; ++a)
        wraw[(size_t)(a0+a)*NJ + j] = acc[a] + bj;
    }
    return;
  }

  // ---------------- feature channel-last transpose, all levels ----------
  const int fb = bid - NFCB;
  const int bc = fb / TPB;
  const int bx = fb % TPB;
  int lvl, px0, ch0;
  const float* src;
  if (bx < 704)      { lvl = 0; src = f0; px0 = (bx >> 2) * 64;         ch0 = (bx & 3) * 64; }
  else if (bx < 880) { lvl = 1; src = f1; px0 = ((bx - 704) >> 2) * 64; ch0 = ((bx - 704) & 3) * 64; }
  else if (bx < 924) { lvl = 2; src = f2; px0 = ((bx - 880) >> 2) * 64; ch0 = ((bx - 880) & 3) * 64; }
  else               { lvl = 3; src = f3; px0 = (bx - 924) * 16;        ch0 = 0; }
  const int HW = cHW[lvl];
  const float* in = src + (size_t)bc * ED * HW;
  float* outp = tfeat + cLOFF[lvl] + (size_t)bc * HW * ED;

  if (lvl < 3) {
    // 64 px x 64 ch tile (HW: 11264=176*64, 2816=44*64, 704=11*64)
    const int pxl = t & 15, cr = t >> 4;          // px quad, ch row
#pragma unroll
    for (int i = 0; i < 4; ++i) {
      const int ch = cr + 16*i;
      const nfloat4 v = __builtin_nontemporal_load(
          reinterpret_cast<const nfloat4*>(in + (size_t)(ch0 + ch)*HW + px0 + 4*pxl));
      smem[(4*pxl+0)*65 + ch] = v.x;
      smem[(4*pxl+1)*65 + ch] = v.y;
      smem[(4*pxl+2)*65 + ch] = v.z;
      smem[(4*pxl+3)*65 + ch] = v.w;
    }
    __syncthreads();
    const int chl = t & 15, pw = t >> 4;
#pragma unroll
    for (int i = 0; i < 4; ++i) {
      const int px = pw + 16*i;
      nfloat4 v;
      v.x = smem[px*65 + 4*chl + 0];
      v.y = smem[px*65 + 4*chl + 1];
      v.z = smem[px*65 + 4*chl + 2];
      v.w = smem[px*65 + 4*chl + 3];
      __builtin_nontemporal_store(v,
          reinterpret_cast<nfloat4*>(outp + (size_t)(px0 + px)*ED + ch0 + 4*chl));
    }
  } else {
    // 16 px x 256 ch tile (HW=176 = 11 x 16)
    const int pxl = t & 3, cr = t >> 2;           // cr 0..63
#pragma unroll
    for (int i = 0; i < 4; ++i) {
      const int ch = cr + 64*i;
      const nfloat4 v = __builtin_nontemporal_load(
          reinterpret_cast<const nfloat4*>(in + (size_t)ch*HW + px0 + 4*pxl));
      smem[(4*pxl+0)*257 + ch] = v.x;
      smem[(4*pxl+1)*257 + ch] = v.y;
      smem[(4*pxl+2)*257 + ch] = v.z;
      smem[(4*pxl+3)*257 + ch] = v.w;
    }
    __syncthreads();
    const int chl = t & 63, pw = t >> 6;
#pragma unroll
    for (int i = 0; i < 4; ++i) {
      const int px = pw + 4*i;
      nfloat4 v;
      v.x = smem[px*257 + 4*chl + 0];
      v.y = smem[px*257 + 4*chl + 1];
      v.z = smem[px*257 + 4*chl + 2];
      v.w = smem[px*257 + 4*chl + 3];
      __builtin_nontemporal_store(v,
          reinterpret_cast<nfloat4*>(outp + (size_t)(px0 + px)*ED + 4*chl));
    }
  }
}

// ------- fused: softmax + projection + branchless compacted gather ----
// grid (NBA, SPLIT); CL=true: ALL levels channel-last from tfeat (coalesced
// 1KB taps). CL=false fallback: direct channel-first reads.
template<bool CL>
__global__ __launch_bounds__(256) void k_sample_h(
    const float* __restrict__ anchor, const float* __restrict__ proj,
    const float* __restrict__ wh, const float* __restrict__ wraw,
    const float* __restrict__ tfeat,
    const float* __restrict__ f0, const float* __restrict__ f1,
    const float* __restrict__ f2, const float* __restrict__ f3,
    float* __restrict__ fused)
{
  __shared__ float wsh[NJ];              // [g][e] layout (conflict-free)
  __shared__ float gridsh[NCAM][NP][2];
  __shared__ const float* cptr[EHALF][4]; // 4 pre-clamped tap pointers (ch 0)
  __shared__ float4 cwt[EHALF];           // validity-masked bilinear weights
  __shared__ int2   cmeta[EHALF];         // x=chstep, y=entry idx
  __shared__ int wcnt[4];

  const int ba   = blockIdx.x;
  const int half = blockIdx.y;
  const int b    = ba / A;
  const int t    = threadIdx.x;

  for (int j = t; j < NJ; j += 256)
    wsh[(j & 7) * NE + (j >> 3)] = wraw[(size_t)ba*NJ + j];

  if (t < NCAM*NP) {
    const int c = t / NP, p = t % NP;
    const float* an = anchor + (size_t)ba * 8;
    const float sx = expf(an[3]), sy = expf(an[4]), sz = expf(an[5]);
    const float sn = an[6], cs = an[7];
    const float kx = FIXS[p][0]*sx, ky = FIXS[p][1]*sy, kz = FIXS[p][2]*sz;
    const float px = cs*kx - sn*ky + an[0];
    const float py = sn*kx + cs*ky + an[1];
    const float pz = kz + an[2];
    const float* P = proj + ((size_t)(b*NCAM + c))*16;
    const float X = P[0]*px + P[1]*py + P[2]*pz  + P[3];
    const float Y = P[4]*px + P[5]*py + P[6]*pz  + P[7];
    const float Z = P[8]*px + P[9]*py + P[10]*pz + P[11];
    const float zc  = fmaxf(Z, 1e-5f);
    const float whx = fmaxf(wh[(b*NCAM+c)*2+0], 1e-5f);
    const float why = fmaxf(wh[(b*NCAM+c)*2+1], 1e-5f);
    gridsh[c][p][0] = (X/zc/whx)*2.f - 1.f;
    gridsh[c][p][1] = (Y/zc/why)*2.f - 1.f;
  }
  __syncthreads();

  // entries for this block: e = half*EHALF + (t if t < EHALF)
  bool valid = false;
  int chstep = 0;
  float4 w4 = make_float4(0.f,0.f,0.f,0.f);
  const float *p00=nullptr, *p10=nullptr, *p01=nullptr, *p11=nullptr;
  const int e = half * EHALF + t;
  if (t < EHALF) {
    const int c = e / (NL*NP); const int r = e % (NL*NP);
    const int l = r / NP, p = r % NP;
    const int Wl = cW[l], Hl = cH[l], HWl = cHW[l];
    const float gx = (gridsh[c][p][0] + 1.f) * (Wl * 0.5f) - 0.5f;
    const float gy = (gridsh[c][p][1] + 1.f) * (Hl * 0.5f) - 0.5f;
    const float x0f = floorf(gx), y0f = floorf(gy);
    const bool vx0 = (x0f >=  0.f) & (x0f <= (float)(Wl-1));
    const bool vx1 = (x0f >= -1.f) & (x0f <= (float)(Wl-2));
    const bool vy0 = (y0f >=  0.f) & (y0f <= (float)(Hl-1));
    const bool vy1 = (y0f >= -1.f) & (y0f <= (float)(Hl-2));
    if (vx0|vx1|vy0|vy1) {
      const float wx1 = gx - x0f, wy1 = gy - y0f;
      // clamp both tap coords into the image; invalid taps get weight 0
      const int x0 = (int)fmaxf(fminf(x0f,        (float)(Wl-1)), 0.f);
      const int x1 = (int)fmaxf(fminf(x0f + 1.f,  (float)(Wl-1)), 0.f);
      const int y0 = (int)fmaxf(fminf(y0f,        (float)(Hl-1)), 0.f);
      const int y1 = (int)fmaxf(fminf(y0f + 1.f,  (float)(Hl-1)), 0.f);
      w4 = make_float4((1.f-wx1)*(1.f-wy1)*(vx0&&vy0),
                       wx1*(1.f-wy1)*(vx1&&vy0),
                       (1.f-wx1)*wy1*(vx0&&vy1),
                       wx1*wy1*(vx1&&vy1));
      if (w4.x != 0.f || w4.y != 0.f || w4.z != 0.f || w4.w != 0.f) {
        const float* base;
        int estep;  // element stride for one pixel step
        if (CL) {
          base = tfeat + cLOFF[l] + (size_t)(b*NCAM + c) * HWl * ED;
          estep = ED; chstep = 1;
        } else {
          const float* fp = (l==0)?f0:(l==1)?f1:(l==2)?f2:f3;
          base = fp + (size_t)(b*NCAM + c) * ED * HWl;
          estep = 1; chstep = HWl;
        }
        p00 = base + (size_t)(y0*Wl + x0) * estep;
        p10 = base + (size_t)(y0*Wl + x1) * estep;
        p01 = base + (size_t)(y1*Wl + x0) * estep;
        p11 = base + (size_t)(y1*Wl + x1) * estep;
        valid = true;
      }
    }
  }

  const unsigned long long mask = __ballot(valid);
  const int lane = t & 63, wv = t >> 6;
  if (lane == 0) wcnt[wv] = __popcll(mask);
  __syncthreads();
  int off = 0, nv = 0;
#pragma unroll
  for (int i = 0; i < 4; ++i) { if (i < wv) off += wcnt[i]; nv += wcnt[i]; }
  if (valid) {
    const int pos = off + __popcll(mask & ((1ull << lane) - 1ull));
    cptr[pos][0] = p00; cptr[pos][1] = p10; cptr[pos][2] = p01; cptr[pos][3] = p11;
    cwt[pos]   = w4;
    cmeta[pos] = make_int2(chstep, e);
  }

  // group softmax over ALL entries (needed for correct normalization)
  {
    const int g = t >> 5, ln = t & 31;
    float* wg = wsh + g * NE;
    float m = -3.4e38f;
    for (int i = ln; i < NE; i += 32) m = fmaxf(m, wg[i]);
#pragma unroll
    for (int mk = 16; mk >= 1; mk >>= 1) m = fmaxf(m, __shfl_xor(m, mk));
    float s = 0.f;
    for (int i = ln; i < NE; i += 32) {
      const float ev = expf(wg[i] - m);
      wg[i] = ev;
      s += ev;
    }
#pragma unroll
    for (int mk = 16; mk >= 1; mk >>= 1) s += __shfl_xor(s, mk);
    const float inv = 1.f / s;
    for (int i = ln; i < NE; i += 32) wg[i] *= inv;
  }
  __syncthreads();

  float acc = 0.f;
  const int g = t >> 5;
#pragma unroll 4
  for (int i = 0; i < nv; ++i) {
    const int2 m = cmeta[i];
    const size_t toff = (size_t)t * m.x;
    const float4 w = cwt[i];
    const float aw = wsh[g*NE + m.y];
    const float v00 = cptr[i][0][toff];
    const float v10 = cptr[i][1][toff];
    const float v01 = cptr[i][2][toff];
    const float v11 = cptr[i][3][toff];
    acc += aw * (w.x*v00 + w.y*v10 + w.z*v01 + w.w*v11);
  }
  fused[((size_t)half * NBA + ba) * ED + t] = acc;
}

// ---------------- out = (fused0+fused1) @ w_out^T + b_out ----------------
__global__ __launch_bounds__(256) void k_out(const float* __restrict__ fused,
    const float* __restrict__ w_out, const float* __restrict__ b_out,
    float* __restrict__ out)
{
  __shared__ float fsh[8][ED];
  const int a0 = blockIdx.x * 8;
  const int t = threadIdx.x;
#pragma unroll
  for (int k = 0; k < 8; ++k)
    fsh[k][t] = fused[(size_t)(a0+k)*ED + t]
              + fused[(size_t)NBA*ED + (size_t)(a0+k)*ED + t];
  __syncthreads();
  float acc[8] = {0.f,0.f,0.f,0.f,0.f,0.f,0.f,0.f};
  for (int i = 0; i < ED; i += 4) {
    const float4 w4 = *(const float4*)&w_out[(size_t)t*ED + i];
#pragma unroll
    for (int k = 0; k < 8; ++k) {
      const float4 fv = *(const float4*)&fsh[k][i];
      acc[k] += w4.x*fv.x + w4.y*fv.y + w4.z*fv.z + w4.w*fv.w;
    }
  }
  const float bo = b_out[t];
#pragma unroll
  for (int k = 0; k < 8; ++k) out[(size_t)(a0+k)*ED + t] = acc[k] + bo;
}

extern "C" void kernel_launch(void* const* d_in, const int* in_sizes, int n_in,
                              void* d_out, int out_size, void* d_ws, size_t ws_size,
                              hipStream_t stream) {
  const float* inst   = (const float*)d_in[0];
  const float* anchor = (const float*)d_in[1];
  const float* emb    = (const float*)d_in[2];
  const float* f0 = (const float*)d_in[3];
  const float* f1 = (const float*)d_in[4];
  const float* f2 = (const float*)d_in[5];
  const float* f3 = (const float*)d_in[6];
  const float* proj  = (const float*)d_in[7];
  const float* wh    = (const float*)d_in[8];
  const float* w_fc  = (const float*)d_in[9];
  const float* b_fc  = (const float*)d_in[10];
  const float* w_out = (const float*)d_in[11];
  const float* b_out = (const float*)d_in[12];
  float* out = (float*)d_out;
  float* ws  = (float*)d_ws;

  const size_t TFEAT = 45957120ULL;   // ALL levels channel-last, floats
  const size_t WRAW  = (size_t)NBA * NJ;
  const size_t FUSED = (size_t)SPLIT * NBA * ED;
  const bool tr = ws_size >= (TFEAT + WRAW + FUSED) * sizeof(float);

  float* tfeat  = ws;
  float* wraw   = tr ? (ws + TFEAT) : ws;
  float* fusedp = wraw + WRAW;

  // merged: FC (1575 blocks, first) + channel-last feat transpose (11220)
  k_prep<<<NFCB + (tr ? NTRB : 0), 256, 0, stream>>>(f0, f1, f2, f3,
      inst, emb, w_fc, b_fc, tfeat, wraw);

  if (tr)
    k_sample_h<true><<<dim3(NBA, SPLIT), 256, 0, stream>>>(anchor, proj, wh,
        wraw, tfeat, f0, f1, f2, f3, fusedp);
  else
    k_sample_h<false><<<dim3(NBA, SPLIT), 256, 0, stream>>>(anchor, proj, wh,
        wraw, tfeat, f0, f1, f2, f3, fusedp);

  k_out<<<NBA / 8, 256, 0, stream>>>(fusedp, w_out, b_out, out);
}